// Round 1
// baseline (55.064 us; speedup 1.0000x reference)
//
#include <hip/hip_runtime.h>
#include <math.h>

#define DHW (128*128*128)        // 2,097,152 voxels per (b,c) plane
#define QUADS (DHW/4)            // 524,288 float4 quads per plane
#define NBLK_PER_B 256
#define NTHR 256
#define HID 16
#define CIN 4
#define NGRP 4

__device__ __forceinline__ float wave_sum(float v) {
#pragma unroll
  for (int off = 32; off > 0; off >>= 1) v += __shfl_xor(v, off, 64);
  return v;
}

// Kernel 1: compute h = conv1(x) on the fly, accumulate per-(batch,group)
// sum and sumsq into per-block partials (deterministic).
__global__ __launch_bounds__(NTHR) void k_stats_partial(
    const float* __restrict__ x, const float* __restrict__ w1,
    const float* __restrict__ b1, float* __restrict__ partial)
{
  const int blk = blockIdx.x;        // 0..511
  const int b   = blk >> 8;          // batch
  const int lb  = blk & 255;         // block within batch
  const float* xb = x + (size_t)b * CIN * DHW;

  float W[HID][CIN], Bb[HID];
#pragma unroll
  for (int o = 0; o < HID; ++o) {
    Bb[o] = b1[o];
#pragma unroll
    for (int c = 0; c < CIN; ++c) W[o][c] = w1[o*CIN + c];
  }

  float sum[NGRP] = {0.f,0.f,0.f,0.f};
  float ssq[NGRP] = {0.f,0.f,0.f,0.f};

  const int q0 = lb * NTHR + threadIdx.x;
#pragma unroll 1
  for (int it = 0; it < 8; ++it) {
    const int q = q0 + it * (NBLK_PER_B * NTHR);
    float4 xc[CIN];
#pragma unroll
    for (int c = 0; c < CIN; ++c)
      xc[c] = ((const float4*)(xb + (size_t)c * DHW))[q];
#pragma unroll
    for (int v = 0; v < 4; ++v) {
      float xv[CIN];
#pragma unroll
      for (int c = 0; c < CIN; ++c) xv[c] = ((const float*)&xc[c])[v];
#pragma unroll
      for (int o = 0; o < HID; ++o) {
        float h = Bb[o];
#pragma unroll
        for (int c = 0; c < CIN; ++c) h = fmaf(W[o][c], xv[c], h);
        const int g = o >> 2;
        sum[g] += h;
        ssq[g] = fmaf(h, h, ssq[g]);
      }
    }
  }

  __shared__ float lds[4][8];
  const int wave = threadIdx.x >> 6, lane = threadIdx.x & 63;
#pragma unroll
  for (int i = 0; i < 8; ++i) {
    float v = (i < 4) ? sum[i] : ssq[i - 4];
    v = wave_sum(v);
    if (lane == 0) lds[wave][i] = v;
  }
  __syncthreads();
  if (threadIdx.x < 8) {
    float v = lds[0][threadIdx.x] + lds[1][threadIdx.x]
            + lds[2][threadIdx.x] + lds[3][threadIdx.x];
    partial[blk * 8 + threadIdx.x] = v;
  }
}

// Kernel 2: reduce 256 partials per (b,g) -> mean, rstd. 8 blocks.
__global__ __launch_bounds__(NTHR) void k_stats_final(
    const float* __restrict__ partial, float* __restrict__ stats)
{
  const int bg = blockIdx.x;               // 0..7  (b*4+g)
  const int b = bg >> 2, g = bg & 3;
  const int blk = b * NBLK_PER_B + threadIdx.x;
  float s = partial[blk * 8 + g];
  float q = partial[blk * 8 + 4 + g];
  s = wave_sum(s);
  q = wave_sum(q);
  __shared__ float lds[4][2];
  const int wave = threadIdx.x >> 6, lane = threadIdx.x & 63;
  if (lane == 0) { lds[wave][0] = s; lds[wave][1] = q; }
  __syncthreads();
  if (threadIdx.x == 0) {
    const float S = lds[0][0] + lds[1][0] + lds[2][0] + lds[3][0];
    const float Q = lds[0][1] + lds[1][1] + lds[2][1] + lds[3][1];
    const float n = (float)((size_t)CIN * DHW);  // 4 group-channels * DHW
    const float mean = S / n;
    const float var  = Q / n - mean * mean;
    stats[bg * 2 + 0] = mean;
    stats[bg * 2 + 1] = rsqrtf(var + 1e-5f);
  }
}

// Kernel 3: full fused apply pass.
__global__ __launch_bounds__(NTHR) void k_apply(
    const float* __restrict__ x,
    const float* __restrict__ w1, const float* __restrict__ b1,
    const float* __restrict__ gnw, const float* __restrict__ gnb,
    const float* __restrict__ w2, const float* __restrict__ b2,
    const float* __restrict__ temp, const float* __restrict__ rsc,
    const float* __restrict__ stats, float* __restrict__ out)
{
  const int blk = blockIdx.x;
  const int b   = blk >> 8;
  const int lb  = blk & 255;
  const float* xb = x   + (size_t)b * CIN * DHW;
  float*       ob = out + (size_t)b * CIN * DHW;

  const float invT   = 1.0f / (fabsf(temp[0]) + 1e-6f);
  const float rs     = rsc[0];
  const float onemrs = 1.0f - rs;

  // Fold GroupNorm (mean, rstd, affine) into conv1 weights for this batch.
  float W1[HID][CIN], B1[HID];
#pragma unroll
  for (int o = 0; o < HID; ++o) {
    const int g = o >> 2;
    const float mean = stats[(b * NGRP + g) * 2 + 0];
    const float rstd = stats[(b * NGRP + g) * 2 + 1];
    const float s = rstd * gnw[o];
    const float t = gnb[o] - mean * s;
    B1[o] = fmaf(b1[o], s, t);
#pragma unroll
    for (int c = 0; c < CIN; ++c) W1[o][c] = w1[o*CIN + c] * s;
  }
  float W2[CIN][HID], B2[CIN];
#pragma unroll
  for (int c = 0; c < CIN; ++c) {
    B2[c] = b2[c];
#pragma unroll
    for (int o = 0; o < HID; ++o) W2[c][o] = w2[c*HID + o];
  }

  const int q0 = lb * NTHR + threadIdx.x;
#pragma unroll 1
  for (int it = 0; it < 8; ++it) {
    const int q = q0 + it * (NBLK_PER_B * NTHR);
    float4 xc[CIN], oc[CIN];
#pragma unroll
    for (int c = 0; c < CIN; ++c)
      xc[c] = ((const float4*)(xb + (size_t)c * DHW))[q];
#pragma unroll
    for (int v = 0; v < 4; ++v) {
      float xv[CIN];
#pragma unroll
      for (int c = 0; c < CIN; ++c) xv[c] = ((const float*)&xc[c])[v];
      // conv1 + folded GN + LeakyReLU(0.1)
      float hn[HID];
#pragma unroll
      for (int o = 0; o < HID; ++o) {
        float h = B1[o];
#pragma unroll
        for (int c = 0; c < CIN; ++c) h = fmaf(W1[o][c], xv[c], h);
        hn[o] = (h > 0.0f) ? h : 0.1f * h;
      }
      // conv2 -> tanh -> temperature softmax
      float e[CIN], esum = 0.0f;
#pragma unroll
      for (int c = 0; c < CIN; ++c) {
        float z = B2[c];
#pragma unroll
        for (int o = 0; o < HID; ++o) z = fmaf(W2[c][o], hn[o], z);
        // tanh(z) = 1 - 2/(exp(2z)+1); exact at +-inf limits
        const float ez = __expf(2.0f * z);
        const float th = 1.0f - 2.0f * __builtin_amdgcn_rcpf(ez + 1.0f);
        e[c] = __expf(th * invT);   // |th*invT| <= 3.34, no overflow
        esum += e[c];
      }
      const float rdenom = __builtin_amdgcn_rcpf(esum);
#pragma unroll
      for (int c = 0; c < CIN; ++c) {
        const float wgt = e[c] * rdenom;
        ((float*)&oc[c])[v] = xv[c] * fmaf(wgt, rs, onemrs);
      }
    }
#pragma unroll
    for (int c = 0; c < CIN; ++c)
      ((float4*)(ob + (size_t)c * DHW))[q] = oc[c];
  }
}

extern "C" void kernel_launch(void* const* d_in, const int* in_sizes, int n_in,
                              void* d_out, int out_size, void* d_ws, size_t ws_size,
                              hipStream_t stream) {
  const float* x    = (const float*)d_in[0];
  const float* w1   = (const float*)d_in[1];
  const float* b1   = (const float*)d_in[2];
  const float* gnw  = (const float*)d_in[3];
  const float* gnb  = (const float*)d_in[4];
  const float* w2   = (const float*)d_in[5];
  const float* b2   = (const float*)d_in[6];
  const float* temp = (const float*)d_in[7];
  const float* rsc  = (const float*)d_in[8];
  float* out = (float*)d_out;

  float* partial = (float*)d_ws;          // 512 blocks * 8 floats = 16 KB
  float* stats   = partial + 512 * 8;     // 16 floats (mean,rstd per b,g)

  k_stats_partial<<<512, NTHR, 0, stream>>>(x, w1, b1, partial);
  k_stats_final<<<8, NTHR, 0, stream>>>(partial, stats);
  k_apply<<<512, NTHR, 0, stream>>>(x, w1, b1, gnw, gnb, w2, b2,
                                    temp, rsc, stats, out);
}